// Round 6
// baseline (305.354 us; speedup 1.0000x reference)
//
#include <hip/hip_runtime.h>

#define DIM 128
#define HEADS 8
#define PHC 16

// bucket sort: 64 nodes per bucket, padded per-bucket regions
#define BSHIFT 6
#define BNODES 64
#define CAP 1408     // mean fill = E*64/n ~ 1024, sigma ~ 32; +12 sigma
#define NBMAX 1600   // >= ceil(n/64)

typedef __bf16 bf16x4 __attribute__((ext_vector_type(4)));
typedef __bf16 bf16x8 __attribute__((ext_vector_type(8)));
typedef float  f32x4  __attribute__((ext_vector_type(4)));

__device__ inline unsigned short f2bf(float x) {
  unsigned int u = __float_as_uint(x);
  unsigned int r = (u + 0x7FFF + ((u >> 16) & 1)) >> 16;  // round-to-nearest-even
  return (unsigned short)r;
}

// ---------------------------------------------------------------------------
// Kernel 0: pre-pack W into bf16 hi/lo B-fragments in MFMA fragment order,
// and zero the bucket cursors (must precede the fused gemm+scatter kernel).
// ---------------------------------------------------------------------------
__global__ __launch_bounds__(256) void k_prepw(
    const float* __restrict__ W, __bf16* __restrict__ Wh,
    __bf16* __restrict__ Wl, int* __restrict__ gCursor, int NB) {
  const int tuple = blockIdx.x * 256 + threadIdx.x;   // 0..2047
  if (tuple < NB) gCursor[tuple] = 0;
  const int ln = tuple & 15;
  const int lg = (tuple >> 4) & 3;
  const int cg = (tuple >> 6) & 7;
  const int kt = tuple >> 9;
  const int col = (cg << 4) + ln;
  bf16x8 h, l;
#pragma unroll
  for (int e = 0; e < 8; ++e) {
    int k = (kt << 5) + ((e >> 2) << 4) + (lg << 2) + (e & 3);
    float wv = W[k * DIM + col];
    __bf16 hh = (__bf16)wv;
    h[e] = hh;
    l[e] = (__bf16)(wv - (float)hh);
  }
  *(bf16x8*)(Wh + tuple * 8) = h;
  *(bf16x8*)(Wl + tuple * 8) = l;
}

// ---------------------------------------------------------------------------
// Kernel 1 (FUSED): role-split grid. Blocks [0, nScat) bucket the edge list;
// blocks [nScat, ...) run the MFMA GEMM. nt is written TRANSPOSED into 8
// head-planes nt_t[h][node][16ch bf16 = 32B] (3.2 MB/plane) and
// s_exp_t[h][node] (400 KB/plane) so the aggregation kernel can pin one
// plane per XCD L2.
// ---------------------------------------------------------------------------
#define GROWS 64

__global__ __launch_bounds__(256, 3) void k_gemm_scatter(
    const float* __restrict__ A, const __bf16* __restrict__ Wh,
    const __bf16* __restrict__ Wl, const float* __restrict__ bias,
    const float* __restrict__ attn_w, unsigned int* __restrict__ nt_t,
    float* __restrict__ s_exp_t, const int* __restrict__ send,
    const int* __restrict__ recv, int* __restrict__ gCursor,
    unsigned int* __restrict__ pairs, int E, int NB, int nScat, int n) {
  __shared__ __align__(16) float smemF[GROWS * DIM];   // 32 KB, aliased

  if (blockIdx.x < nScat) {
    // ---------------- scatter role: bucket edges by recv>>6 ----------------
    int* cnt = (int*)smemF;
    int* cur = cnt + NBMAX;           // 12.8 KB of the 32 KB
    const int t = threadIdx.x;
    for (int i = t; i < NB; i += 256) cnt[i] = 0;
    __syncthreads();
    const int e0 = blockIdx.x * 8192;
    const int e1 = min(e0 + 8192, E);
    for (int i = e0 + t; i < e1; i += 256)
      atomicAdd(&cnt[recv[i] >> BSHIFT], 1);
    __syncthreads();
    for (int i = t; i < NB; i += 256) {
      int c = cnt[i];
      cur[i] = i * CAP + (c ? atomicAdd(&gCursor[i], c) : 0);
    }
    __syncthreads();
    for (int i = e0 + t; i < e1; i += 256) {
      int r = recv[i];
      int b = r >> BSHIFT;
      int p = atomicAdd(&cur[b], 1);
      if (p - b * CAP < CAP)   // overflow guard (P ~ 0 at +12 sigma)
        pairs[p] = (unsigned int)send[i] | ((unsigned int)(r & (BNODES - 1)) << 17);
    }
    return;
  }

  // ------------------------------ gemm role -------------------------------
  __bf16* Ah = (__bf16*)smemF;          // [64 rows][16 units][8] bf16 hi
  __bf16* Al = Ah + GROWS * DIM;        // same, lo
  const int t    = threadIdx.x;
  const int row0 = (blockIdx.x - nScat) * GROWS;
  const int lane = t & 63;
  const int w    = t >> 6;       // wave id: cols [32w, 32w+32)
  const int lg   = lane >> 4;    // k-group
  const int ln   = lane & 15;    // fragment row (A) / col (B,D)

  // ---- A-tile global loads
  float4 av[8];
  {
    const float4* A4 = (const float4*)(A + (size_t)row0 * DIM);
    const int lim = min(GROWS, n - row0) * (DIM / 4);
#pragma unroll
    for (int j = 0; j < 8; ++j) {
      int i = t + j * 256;
      av[j] = (i < lim) ? A4[i] : make_float4(0.f, 0.f, 0.f, 0.f);
    }
  }

  // ---- convert to bf16 hi/lo, store fragment-ordered + swizzled.
#pragma unroll
  for (int j = 0; j < 8; ++j) {
    int i = t + j * 256;
    int r = i >> 5, c4 = i & 31;
    int ktc = c4 >> 3, lgc = c4 & 3, ehi = (c4 >> 2) & 1;
    int unit = (r << 4) + (((ktc << 2) + lgc) ^ (r & 15));
    int ei = (unit << 3) + (ehi << 2);
    float x0 = av[j].x, x1 = av[j].y, x2 = av[j].z, x3 = av[j].w;
    __bf16 h0 = (__bf16)x0, h1 = (__bf16)x1, h2 = (__bf16)x2, h3 = (__bf16)x3;
    bf16x4 hv = {h0, h1, h2, h3};
    bf16x4 lv = {(__bf16)(x0 - (float)h0), (__bf16)(x1 - (float)h1),
                 (__bf16)(x2 - (float)h2), (__bf16)(x3 - (float)h3)};
    *(bf16x4*)(Ah + ei) = hv;
    *(bf16x4*)(Al + ei) = lv;
  }

  f32x4 acc[4][2];
  {
    const float b0 = bias[(w << 5) + ln];
    const float b1 = bias[(w << 5) + 16 + ln];
#pragma unroll
    for (int rt = 0; rt < 4; ++rt) {
      acc[rt][0] = (f32x4){b0, b0, b0, b0};
      acc[rt][1] = (f32x4){b1, b1, b1, b1};
    }
  }
  __syncthreads();

  // ---- main loop: 4 k-steps x {4 W vec-loads, 8 ds_read_b128, 24 MFMA}
  const int cg0 = w << 1;
#pragma unroll
  for (int kt = 0; kt < 4; ++kt) {
    bf16x8 Bh0, Bl0, Bh1, Bl1;
    {
      int i0 = ((((kt << 3) + cg0) << 2) + lg) * 16 + ln;      // ct = 0
      int i1 = ((((kt << 3) + cg0 + 1) << 2) + lg) * 16 + ln;  // ct = 1
      Bh0 = *(const bf16x8*)(Wh + (i0 << 3));
      Bl0 = *(const bf16x8*)(Wl + (i0 << 3));
      Bh1 = *(const bf16x8*)(Wh + (i1 << 3));
      Bl1 = *(const bf16x8*)(Wl + (i1 << 3));
    }
    bf16x8 ah[4], al[4];
#pragma unroll
    for (int rt = 0; rt < 4; ++rt) {
      int m = (rt << 4) + ln;
      int u = (m << 4) + (((kt << 2) + lg) ^ (m & 15));
      ah[rt] = *(const bf16x8*)(Ah + (u << 3));
      al[rt] = *(const bf16x8*)(Al + (u << 3));
    }
#pragma unroll
    for (int rt = 0; rt < 4; ++rt) {
      acc[rt][0] = __builtin_amdgcn_mfma_f32_16x16x32_bf16(ah[rt], Bh0, acc[rt][0], 0, 0, 0);
      acc[rt][0] = __builtin_amdgcn_mfma_f32_16x16x32_bf16(ah[rt], Bl0, acc[rt][0], 0, 0, 0);
      acc[rt][0] = __builtin_amdgcn_mfma_f32_16x16x32_bf16(al[rt], Bh0, acc[rt][0], 0, 0, 0);
      acc[rt][1] = __builtin_amdgcn_mfma_f32_16x16x32_bf16(ah[rt], Bh1, acc[rt][1], 0, 0, 0);
      acc[rt][1] = __builtin_amdgcn_mfma_f32_16x16x32_bf16(ah[rt], Bl1, acc[rt][1], 0, 0, 0);
      acc[rt][1] = __builtin_amdgcn_mfma_f32_16x16x32_bf16(al[rt], Bh1, acc[rt][1], 0, 0, 0);
    }
  }

  __syncthreads();   // all waves done with Ah/Al -> reuse LDS as f32 scratch

  // ---- scatter D-fragments to LDS f32 [64][128] (col bit4 ^= row bit2)
#pragma unroll
  for (int rt = 0; rt < 4; ++rt)
#pragma unroll
    for (int ct = 0; ct < 2; ++ct) {
      int colx = ((w << 5) + (ct << 4) + ln) ^ ((lg & 1) << 4);
#pragma unroll
      for (int r = 0; r < 4; ++r) {
        int rowl = (rt << 4) + (lg << 2) + r;
        smemF[(rowl << 7) + colx] = acc[rt][ct][r];
      }
    }

  // ---- sender scores from register fragments (transposed planes).
  //      receiver part + attn_b cancel in the segment softmax; |score|<=~6.
  {
    const float aw = attn_w[ln];
#pragma unroll
    for (int rt = 0; rt < 4; ++rt)
#pragma unroll
      for (int ct = 0; ct < 2; ++ct) {
        const int head = (w << 1) + ct;
#pragma unroll
        for (int r = 0; r < 4; ++r) {
          float v = acc[rt][ct][r];
          float p = (v > 0.f ? v : 0.2f * v) * aw;
          p += __shfl_xor(p, 1);
          p += __shfl_xor(p, 2);
          p += __shfl_xor(p, 4);
          p += __shfl_xor(p, 8);
          if (ln == 0) {
            int row = row0 + (rt << 4) + (lg << 2) + r;
            if (row < n) s_exp_t[(size_t)head * n + row] = __expf(p);
          }
        }
      }
  }
  __syncthreads();

  // ---- pack to bf16 from LDS into head-planes: nt_t[h][node][16ch].
  {
    const int nrow = min(GROWS, n - row0);
    const int r = t >> 2;           // 0..63 row in tile
    const int q = t & 3;            // 4-ch group within the head slice
    if (r < nrow) {
#pragma unroll
      for (int j = 0; j < 8; ++j) { // j = head plane
        int c4 = (j << 2) + q;
        int c4s = c4 ^ (((r >> 2) & 1) << 2);   // undo col-bit4 swizzle
        f32x4 v = *(const f32x4*)(smemF + (r << 7) + (c4s << 2));
        unsigned int lo = (unsigned int)f2bf(v[0]) | ((unsigned int)f2bf(v[1]) << 16);
        unsigned int hi = (unsigned int)f2bf(v[2]) | ((unsigned int)f2bf(v[3]) << 16);
        ((uint2*)nt_t)[((size_t)j * n + row0 + r) * 4 + q] = make_uint2(lo, hi);
      }
    }
  }
}

// ---------------------------------------------------------------------------
// Kernel 2: build the per-bucket CSR ONCE (was 8x inside the R5 agg kernel:
// ~50 us of redundant hist/scan/scatter + 4M LDS bank conflicts). Also
// rank-sorts the 64 nodes by degree (exact counting-rank -> permutation) so
// each aggregation wave gets equal-degree nodes (kills the Poisson max-tail
// divergence). Slot meta packed: eoff(11b)<<17 | deg(11b)<<6 | node(6b).
// ---------------------------------------------------------------------------
__global__ __launch_bounds__(256) void k_buildcsr(
    const unsigned int* __restrict__ pairs, const int* __restrict__ gCursor,
    int* __restrict__ csr_g, unsigned int* __restrict__ meta_g) {
  __shared__ unsigned int buf[CAP];
  __shared__ int hist[BNODES], curl[BNODES];
  __shared__ unsigned int slotmeta[BNODES];
  const int b = blockIdx.x;
  const int t = threadIdx.x;
  const int base = b * CAP;
  const int bsize = min(gCursor[b], CAP);

  for (int i = t; i < bsize; i += 256) buf[i] = pairs[base + i];
  if (t < BNODES) hist[t] = 0;
  __syncthreads();
  for (int i = t; i < bsize; i += 256)
    atomicAdd(&hist[(buf[i] >> 17) & (BNODES - 1)], 1);
  __syncthreads();
  if (t < 64) {   // wave 0: scan for offsets + counting-rank degree sort
    int v = hist[t];
    int x = v;
#pragma unroll
    for (int off = 1; off < 64; off <<= 1) {
      int y = __shfl_up(x, off);
      if (t >= off) x += y;
    }
    int e = x - v;          // exclusive offset
    curl[t] = e;
    int rank = 0;
    for (int j = 0; j < 64; ++j) {
      int dj = hist[j];
      rank += (dj > v) || (dj == v && j < t);
    }
    slotmeta[rank] = ((unsigned int)e << 17) | ((unsigned int)v << 6) |
                     (unsigned int)t;
  }
  __syncthreads();
  if (t < 64) meta_g[(b << 6) + t] = slotmeta[t];
  for (int i = t; i < bsize; i += 256) {
    unsigned int v = buf[i];
    int p = atomicAdd(&curl[(v >> 17) & (BNODES - 1)], 1);
    csr_g[base + p] = (int)(v & 0x1FFFF);
  }
}

// ---------------------------------------------------------------------------
// Kernel 3: aggregation only. Grid NB*8, block = (bucket, head) with
// head = blockIdx & 7 -> HW round-robin pins each head's 3.6 MB plane to one
// XCD L2 (R5-verified: FETCH 278->40 MB). CSR read nontemporal (streams via
// L3, protects plane residency). 4-lane team per degree-sorted slot.
// ---------------------------------------------------------------------------
__global__ __launch_bounds__(256) void k_agg(
    const int* __restrict__ csr_g, const int* __restrict__ gCursor,
    const unsigned int* __restrict__ meta_g, const unsigned int* __restrict__ nt_t,
    const float* __restrict__ s_exp_t, float* __restrict__ out, int n) {
  __shared__ int csr_l[CAP];
  __shared__ unsigned int smeta[BNODES];
  const int b = blockIdx.x >> 3;
  const int h = blockIdx.x & 7;     // head plane; %8 ~ XCD round-robin
  const int t = threadIdx.x;
  const int bsize = min(gCursor[b], CAP);

  for (int i = t; i < bsize; i += 256)
    csr_l[i] = __builtin_nontemporal_load(&csr_g[b * CAP + i]);
  if (t < BNODES) smeta[t] = meta_g[(b << 6) + t];
  __syncthreads();

  const int nl = t >> 2;          // slot (degree-sorted)
  const int q  = t & 3;           // 4-ch group within the 16-ch head slice
  const unsigned int m = smeta[nl];
  const int node = (b << BSHIFT) + (int)(m & 63);
  const int deg  = (int)((m >> 6) & 0x7FF);
  const int eoff = (int)(m >> 17);
  const uint2* nt2 = (const uint2*)nt_t;
  const float* sp = s_exp_t + (size_t)h * n;
  const size_t pb4 = (size_t)h * n * 4;   // plane base in uint2 units

  f32x4 a = {0.f, 0.f, 0.f, 0.f};
  float den = 0.f;
  for (int j = 0; j < deg; j += 4) {
    bool ok1 = (j + 1) < deg, ok2 = (j + 2) < deg, ok3 = (j + 3) < deg;
    int s0 = csr_l[eoff + j];                       // LDS broadcast (4 lanes)
    int s1 = csr_l[ok1 ? (eoff + j + 1) : eoff];
    int s2 = csr_l[ok2 ? (eoff + j + 2) : eoff];
    int s3 = csr_l[ok3 ? (eoff + j + 3) : eoff];
    float w0 = sp[s0];                              // L2-resident plane
    float w1 = ok1 ? sp[s1] : 0.f;
    float w2 = ok2 ? sp[s2] : 0.f;
    float w3 = ok3 ? sp[s3] : 0.f;
    uint2 q0 = nt2[pb4 + s0 * 4 + q];               // 32B/team, L2-resident
    uint2 q1 = nt2[pb4 + s1 * 4 + q];
    uint2 q2 = nt2[pb4 + s2 * 4 + q];
    uint2 q3 = nt2[pb4 + s3 * 4 + q];
    den += (w0 + w1) + (w2 + w3);
    a.x = fmaf(w0, __uint_as_float(q0.x << 16),
          fmaf(w1, __uint_as_float(q1.x << 16),
          fmaf(w2, __uint_as_float(q2.x << 16),
          fmaf(w3, __uint_as_float(q3.x << 16), a.x))));
    a.y = fmaf(w0, __uint_as_float(q0.x & 0xFFFF0000u),
          fmaf(w1, __uint_as_float(q1.x & 0xFFFF0000u),
          fmaf(w2, __uint_as_float(q2.x & 0xFFFF0000u),
          fmaf(w3, __uint_as_float(q3.x & 0xFFFF0000u), a.y))));
    a.z = fmaf(w0, __uint_as_float(q0.y << 16),
          fmaf(w1, __uint_as_float(q1.y << 16),
          fmaf(w2, __uint_as_float(q2.y << 16),
          fmaf(w3, __uint_as_float(q3.y << 16), a.z))));
    a.w = fmaf(w0, __uint_as_float(q0.y & 0xFFFF0000u),
          fmaf(w1, __uint_as_float(q1.y & 0xFFFF0000u),
          fmaf(w2, __uint_as_float(q2.y & 0xFFFF0000u),
          fmaf(w3, __uint_as_float(q3.y & 0xFFFF0000u), a.w))));
  }
  if (node < n) {
    const float inv = (deg > 0) ? 1.0f / den : 0.f;  // deg==0 -> zeros
    f32x4 o = {a.x * inv, a.y * inv, a.z * inv, a.w * inv};
    // out[node][16h + 4q .. +3]: 64B aligned chunk per (node, head)
    __builtin_nontemporal_store(
        o, (f32x4*)out + (size_t)node * 32 + (h << 2) + q);
  }
}

// ---------------------------------------------------------------------------
extern "C" void kernel_launch(void* const* d_in, const int* in_sizes, int n_in,
                              void* d_out, int out_size, void* d_ws, size_t ws_size,
                              hipStream_t stream) {
  const float* nodes   = (const float*)d_in[0];
  const int*   senders = (const int*)d_in[1];
  const int*   recvs   = (const int*)d_in[2];
  const float* W       = (const float*)d_in[3];
  const float* bias    = (const float*)d_in[4];
  const float* attn_w  = (const float*)d_in[5];
  // d_in[6] = attn_b: cancels in segment softmax, unused.

  const int n = in_sizes[0] / DIM;   // 100000
  const int E = in_sizes[1];         // 1600000
  const int NB = (n + BNODES - 1) >> BSHIFT;   // 1563 buckets

  char* w = (char*)d_ws;
  auto align256 = [](size_t x) { return (x + 255) & ~(size_t)255; };
  size_t off = 0;
  unsigned int* nt_t = (unsigned int*)(w + off); off += align256((size_t)n * DIM * 2);
  float* s_exp_t = (float*)(w + off); off += align256((size_t)n * HEADS * 4);
  unsigned int* pairs = (unsigned int*)(w + off); off += align256((size_t)NB * CAP * 4);
  int* csr_g     = (int*)(w + off);   off += align256((size_t)NB * CAP * 4);
  unsigned int* meta_g = (unsigned int*)(w + off); off += align256((size_t)NB * 64 * 4);
  int* gCursor   = (int*)(w + off);   off += align256((size_t)NB * 4);
  __bf16* Wh     = (__bf16*)(w + off); off += align256((size_t)2048 * 8 * 2);
  __bf16* Wl     = (__bf16*)(w + off); off += align256((size_t)2048 * 8 * 2);
  (void)ws_size;

  k_prepw<<<8, 256, 0, stream>>>(W, Wh, Wl, gCursor, NB);
  const int nScat = (E + 8191) / 8192;                 // 196 scatter blocks
  const int ngemm = (n + GROWS - 1) / GROWS;           // 1563 gemm blocks
  k_gemm_scatter<<<nScat + ngemm, 256, 0, stream>>>(
      nodes, Wh, Wl, bias, attn_w, nt_t, s_exp_t,
      senders, recvs, gCursor, pairs, E, NB, nScat, n);
  k_buildcsr<<<NB, 256, 0, stream>>>(pairs, gCursor, csr_g, meta_g);
  k_agg<<<NB * 8, 256, 0, stream>>>(csr_g, gCursor, meta_g, nt_t, s_exp_t,
                                    (float*)d_out, n);
}

// Round 7
// 261.947 us; speedup vs baseline: 1.1657x; 1.1657x over previous
//
#include <hip/hip_runtime.h>

#define DIM 128
#define HEADS 8
#define PHC 16

// bucket sort: 64 nodes per bucket, padded per-bucket regions
#define BSHIFT 6
#define BNODES 64
#define CAP 1408     // mean fill = E*64/n ~ 1024, sigma ~ 32; +12 sigma
#define NBMAX 1600   // >= ceil(n/64)

typedef __bf16 bf16x4 __attribute__((ext_vector_type(4)));
typedef __bf16 bf16x8 __attribute__((ext_vector_type(8)));
typedef float  f32x4  __attribute__((ext_vector_type(4)));

__device__ inline unsigned short f2bf(float x) {
  unsigned int u = __float_as_uint(x);
  unsigned int r = (u + 0x7FFF + ((u >> 16) & 1)) >> 16;  // round-to-nearest-even
  return (unsigned short)r;
}

// ---------------------------------------------------------------------------
// Kernel 0: pre-pack W into bf16 hi/lo B-fragments in MFMA fragment order,
// and zero the bucket cursors (must precede the fused gemm+scatter kernel).
// ---------------------------------------------------------------------------
__global__ __launch_bounds__(256) void k_prepw(
    const float* __restrict__ W, __bf16* __restrict__ Wh,
    __bf16* __restrict__ Wl, int* __restrict__ gCursor, int NB) {
  const int tuple = blockIdx.x * 256 + threadIdx.x;   // 0..2047
  if (tuple < NB) gCursor[tuple] = 0;
  const int ln = tuple & 15;
  const int lg = (tuple >> 4) & 3;
  const int cg = (tuple >> 6) & 7;
  const int kt = tuple >> 9;
  const int col = (cg << 4) + ln;
  bf16x8 h, l;
#pragma unroll
  for (int e = 0; e < 8; ++e) {
    int k = (kt << 5) + ((e >> 2) << 4) + (lg << 2) + (e & 3);
    float wv = W[k * DIM + col];
    __bf16 hh = (__bf16)wv;
    h[e] = hh;
    l[e] = (__bf16)(wv - (float)hh);
  }
  *(bf16x8*)(Wh + tuple * 8) = h;
  *(bf16x8*)(Wl + tuple * 8) = l;
}

// ---------------------------------------------------------------------------
// Kernel 1 (FUSED): role-split grid. Blocks [0, nScat) bucket the edge list;
// blocks [nScat, ...) run the MFMA GEMM. nt is written into 4 HEAD-PAIR
// planes nt_hp[hp][node][32ch bf16 = 64B record] plus paired exp weights
// s_exp_hp[hp][node][2 floats]: the aggregation reads ONE 64B line per
// edge-head-pair + one 8B exp request (requests halved vs per-head planes;
// R6 showed the gather is request-rate limited at ~183 G req/s).
// ---------------------------------------------------------------------------
#define GROWS 64

__global__ __launch_bounds__(256, 3) void k_gemm_scatter(
    const float* __restrict__ A, const __bf16* __restrict__ Wh,
    const __bf16* __restrict__ Wl, const float* __restrict__ bias,
    const float* __restrict__ attn_w, unsigned int* __restrict__ nt_hp,
    float* __restrict__ s_exp_hp, const int* __restrict__ send,
    const int* __restrict__ recv, int* __restrict__ gCursor,
    unsigned int* __restrict__ pairs, int E, int NB, int nScat, int n) {
  __shared__ __align__(16) float smemF[GROWS * DIM];   // 32 KB, aliased

  if (blockIdx.x < nScat) {
    // ---------------- scatter role: bucket edges by recv>>6 ----------------
    int* cnt = (int*)smemF;
    int* cur = cnt + NBMAX;           // 12.8 KB of the 32 KB
    const int t = threadIdx.x;
    for (int i = t; i < NB; i += 256) cnt[i] = 0;
    __syncthreads();
    const int e0 = blockIdx.x * 8192;
    const int e1 = min(e0 + 8192, E);
    for (int i = e0 + t; i < e1; i += 256)
      atomicAdd(&cnt[recv[i] >> BSHIFT], 1);
    __syncthreads();
    for (int i = t; i < NB; i += 256) {
      int c = cnt[i];
      cur[i] = i * CAP + (c ? atomicAdd(&gCursor[i], c) : 0);
    }
    __syncthreads();
    for (int i = e0 + t; i < e1; i += 256) {
      int r = recv[i];
      int b = r >> BSHIFT;
      int p = atomicAdd(&cur[b], 1);
      if (p - b * CAP < CAP)   // overflow guard (P ~ 0 at +12 sigma)
        pairs[p] = (unsigned int)send[i] | ((unsigned int)(r & (BNODES - 1)) << 17);
    }
    return;
  }

  // ------------------------------ gemm role -------------------------------
  __bf16* Ah = (__bf16*)smemF;          // [64 rows][16 units][8] bf16 hi
  __bf16* Al = Ah + GROWS * DIM;        // same, lo
  const int t    = threadIdx.x;
  const int row0 = (blockIdx.x - nScat) * GROWS;
  const int lane = t & 63;
  const int w    = t >> 6;       // wave id: cols [32w, 32w+32)
  const int lg   = lane >> 4;    // k-group
  const int ln   = lane & 15;    // fragment row (A) / col (B,D)

  // ---- A-tile global loads
  float4 av[8];
  {
    const float4* A4 = (const float4*)(A + (size_t)row0 * DIM);
    const int lim = min(GROWS, n - row0) * (DIM / 4);
#pragma unroll
    for (int j = 0; j < 8; ++j) {
      int i = t + j * 256;
      av[j] = (i < lim) ? A4[i] : make_float4(0.f, 0.f, 0.f, 0.f);
    }
  }

  // ---- convert to bf16 hi/lo, store fragment-ordered + swizzled.
#pragma unroll
  for (int j = 0; j < 8; ++j) {
    int i = t + j * 256;
    int r = i >> 5, c4 = i & 31;
    int ktc = c4 >> 3, lgc = c4 & 3, ehi = (c4 >> 2) & 1;
    int unit = (r << 4) + (((ktc << 2) + lgc) ^ (r & 15));
    int ei = (unit << 3) + (ehi << 2);
    float x0 = av[j].x, x1 = av[j].y, x2 = av[j].z, x3 = av[j].w;
    __bf16 h0 = (__bf16)x0, h1 = (__bf16)x1, h2 = (__bf16)x2, h3 = (__bf16)x3;
    bf16x4 hv = {h0, h1, h2, h3};
    bf16x4 lv = {(__bf16)(x0 - (float)h0), (__bf16)(x1 - (float)h1),
                 (__bf16)(x2 - (float)h2), (__bf16)(x3 - (float)h3)};
    *(bf16x4*)(Ah + ei) = hv;
    *(bf16x4*)(Al + ei) = lv;
  }

  f32x4 acc[4][2];
  {
    const float b0 = bias[(w << 5) + ln];
    const float b1 = bias[(w << 5) + 16 + ln];
#pragma unroll
    for (int rt = 0; rt < 4; ++rt) {
      acc[rt][0] = (f32x4){b0, b0, b0, b0};
      acc[rt][1] = (f32x4){b1, b1, b1, b1};
    }
  }
  __syncthreads();

  // ---- main loop: 4 k-steps x {4 W vec-loads, 8 ds_read_b128, 24 MFMA}
  const int cg0 = w << 1;
#pragma unroll
  for (int kt = 0; kt < 4; ++kt) {
    bf16x8 Bh0, Bl0, Bh1, Bl1;
    {
      int i0 = ((((kt << 3) + cg0) << 2) + lg) * 16 + ln;      // ct = 0
      int i1 = ((((kt << 3) + cg0 + 1) << 2) + lg) * 16 + ln;  // ct = 1
      Bh0 = *(const bf16x8*)(Wh + (i0 << 3));
      Bl0 = *(const bf16x8*)(Wl + (i0 << 3));
      Bh1 = *(const bf16x8*)(Wh + (i1 << 3));
      Bl1 = *(const bf16x8*)(Wl + (i1 << 3));
    }
    bf16x8 ah[4], al[4];
#pragma unroll
    for (int rt = 0; rt < 4; ++rt) {
      int m = (rt << 4) + ln;
      int u = (m << 4) + (((kt << 2) + lg) ^ (m & 15));
      ah[rt] = *(const bf16x8*)(Ah + (u << 3));
      al[rt] = *(const bf16x8*)(Al + (u << 3));
    }
#pragma unroll
    for (int rt = 0; rt < 4; ++rt) {
      acc[rt][0] = __builtin_amdgcn_mfma_f32_16x16x32_bf16(ah[rt], Bh0, acc[rt][0], 0, 0, 0);
      acc[rt][0] = __builtin_amdgcn_mfma_f32_16x16x32_bf16(ah[rt], Bl0, acc[rt][0], 0, 0, 0);
      acc[rt][0] = __builtin_amdgcn_mfma_f32_16x16x32_bf16(al[rt], Bh0, acc[rt][0], 0, 0, 0);
      acc[rt][1] = __builtin_amdgcn_mfma_f32_16x16x32_bf16(ah[rt], Bh1, acc[rt][1], 0, 0, 0);
      acc[rt][1] = __builtin_amdgcn_mfma_f32_16x16x32_bf16(ah[rt], Bl1, acc[rt][1], 0, 0, 0);
      acc[rt][1] = __builtin_amdgcn_mfma_f32_16x16x32_bf16(al[rt], Bh1, acc[rt][1], 0, 0, 0);
    }
  }

  __syncthreads();   // all waves done with Ah/Al -> reuse LDS as f32 scratch

  // ---- scatter D-fragments to LDS f32 [64][128] (col bit4 ^= row bit2)
#pragma unroll
  for (int rt = 0; rt < 4; ++rt)
#pragma unroll
    for (int ct = 0; ct < 2; ++ct) {
      int colx = ((w << 5) + (ct << 4) + ln) ^ ((lg & 1) << 4);
#pragma unroll
      for (int r = 0; r < 4; ++r) {
        int rowl = (rt << 4) + (lg << 2) + r;
        smemF[(rowl << 7) + colx] = acc[rt][ct][r];
      }
    }

  // ---- sender scores from register fragments -> paired exp planes.
  //      receiver part + attn_b cancel in the segment softmax; |score|<=~6.
  {
    const float aw = attn_w[ln];
#pragma unroll
    for (int rt = 0; rt < 4; ++rt)
#pragma unroll
      for (int ct = 0; ct < 2; ++ct) {
        // head = 2w + ct -> head-pair hp = w, parity = ct
#pragma unroll
        for (int r = 0; r < 4; ++r) {
          float v = acc[rt][ct][r];
          float p = (v > 0.f ? v : 0.2f * v) * aw;
          p += __shfl_xor(p, 1);
          p += __shfl_xor(p, 2);
          p += __shfl_xor(p, 4);
          p += __shfl_xor(p, 8);
          if (ln == 0) {
            int row = row0 + (rt << 4) + (lg << 2) + r;
            if (row < n) s_exp_hp[((size_t)w * n + row) * 2 + ct] = __expf(p);
          }
        }
      }
  }
  __syncthreads();

  // ---- pack to bf16 from LDS into head-pair planes:
  //      nt_hp[hp][node][32ch] (64B record). Same f2bf rounding -> absmax
  //      unchanged. Each j writes one head's 16ch slice of its pair plane.
  {
    const int nrow = min(GROWS, n - row0);
    const int r = t >> 2;           // 0..63 row in tile
    const int q = t & 3;            // 4-ch group within the head slice
    if (r < nrow) {
#pragma unroll
      for (int j = 0; j < 8; ++j) { // j = head
        int c4 = (j << 2) + q;
        int c4s = c4 ^ (((r >> 2) & 1) << 2);   // undo col-bit4 swizzle
        f32x4 v = *(const f32x4*)(smemF + (r << 7) + (c4s << 2));
        unsigned int lo = (unsigned int)f2bf(v[0]) | ((unsigned int)f2bf(v[1]) << 16);
        unsigned int hi = (unsigned int)f2bf(v[2]) | ((unsigned int)f2bf(v[3]) << 16);
        ((uint2*)nt_hp)[((size_t)(j >> 1) * n + row0 + r) * 8 + (j & 1) * 4 + q] =
            make_uint2(lo, hi);
      }
    }
  }
}

// ---------------------------------------------------------------------------
// Kernel 2: build the per-bucket CSR once + rank-sort the 64 nodes by degree
// (exact counting-rank -> permutation; equal-degree nodes share a wave).
// Slot meta packed: eoff(11b)<<17 | deg(11b)<<6 | node(6b).
// ---------------------------------------------------------------------------
__global__ __launch_bounds__(256) void k_buildcsr(
    const unsigned int* __restrict__ pairs, const int* __restrict__ gCursor,
    int* __restrict__ csr_g, unsigned int* __restrict__ meta_g) {
  __shared__ unsigned int buf[CAP];
  __shared__ int hist[BNODES], curl[BNODES];
  __shared__ unsigned int slotmeta[BNODES];
  const int b = blockIdx.x;
  const int t = threadIdx.x;
  const int base = b * CAP;
  const int bsize = min(gCursor[b], CAP);

  for (int i = t; i < bsize; i += 256) buf[i] = pairs[base + i];
  if (t < BNODES) hist[t] = 0;
  __syncthreads();
  for (int i = t; i < bsize; i += 256)
    atomicAdd(&hist[(buf[i] >> 17) & (BNODES - 1)], 1);
  __syncthreads();
  if (t < 64) {   // wave 0: scan for offsets + counting-rank degree sort
    int v = hist[t];
    int x = v;
#pragma unroll
    for (int off = 1; off < 64; off <<= 1) {
      int y = __shfl_up(x, off);
      if (t >= off) x += y;
    }
    int e = x - v;          // exclusive offset
    curl[t] = e;
    int rank = 0;
    for (int j = 0; j < 64; ++j) {
      int dj = hist[j];
      rank += (dj > v) || (dj == v && j < t);
    }
    slotmeta[rank] = ((unsigned int)e << 17) | ((unsigned int)v << 6) |
                     (unsigned int)t;
  }
  __syncthreads();
  if (t < 64) meta_g[(b << 6) + t] = slotmeta[t];
  for (int i = t; i < bsize; i += 256) {
    unsigned int v = buf[i];
    int p = atomicAdd(&curl[(v >> 17) & (BNODES - 1)], 1);
    csr_g[base + p] = (int)(v & 0x1FFFF);
  }
}

// ---------------------------------------------------------------------------
// Kernel 3: aggregation. Grid NB*4, block = (bucket, head-pair) with
// hp = blockIdx & 3 -> XCDs {x, x+4} own plane hp=x&3 (each caches it in L2).
// 8-lane team per node: one 64B line per edge-head-pair (uint2/lane) + one
// 8B exp request -> 12.8M total requests (halved vs R6's 25.6M).
// ---------------------------------------------------------------------------
__global__ __launch_bounds__(256) void k_agg(
    const int* __restrict__ csr_g, const int* __restrict__ gCursor,
    const unsigned int* __restrict__ meta_g, const unsigned int* __restrict__ nt_hp,
    const float* __restrict__ s_exp_hp, float* __restrict__ out, int n) {
  __shared__ int csr_l[CAP];
  __shared__ unsigned int smeta[BNODES];
  const int b  = blockIdx.x >> 2;
  const int hp = blockIdx.x & 3;    // head pair; blockIdx%8 ~ XCD round-robin
  const int t = threadIdx.x;
  const int bsize = min(gCursor[b], CAP);

  for (int i = t; i < bsize; i += 256)
    csr_l[i] = __builtin_nontemporal_load(&csr_g[b * CAP + i]);
  if (t < BNODES) smeta[t] = meta_g[(b << 6) + t];
  __syncthreads();

  const int lane8 = t & 7;        // owns channels 4*lane8 .. +3 of the 32
  const int par   = lane8 >> 2;   // head parity within the pair
  const uint2* nt2 = (const uint2*)nt_hp;
  const size_t pb8 = (size_t)hp * n * 8;        // plane base, uint2 units
  const float* spp = s_exp_hp + (size_t)hp * n * 2;

#pragma unroll 1
  for (int pi = 0; pi < 2; ++pi) {
    const int nl = (t >> 3) + (pi << 5);        // degree-sorted slot
    const unsigned int m = smeta[nl];
    const int node = (b << BSHIFT) + (int)(m & 63);
    const int deg  = (int)((m >> 6) & 0x7FF);
    const int eoff = (int)(m >> 17);
    f32x4 a = {0.f, 0.f, 0.f, 0.f};
    float den = 0.f;
    for (int j = 0; j < deg; j += 4) {
      bool ok1 = (j + 1) < deg, ok2 = (j + 2) < deg, ok3 = (j + 3) < deg;
      int s0 = csr_l[eoff + j];                 // LDS broadcast (8 lanes)
      int s1 = csr_l[ok1 ? (eoff + j + 1) : eoff];
      int s2 = csr_l[ok2 ? (eoff + j + 2) : eoff];
      int s3 = csr_l[ok3 ? (eoff + j + 3) : eoff];
      float w0 = spp[s0 * 2 + par];             // 8B line / team
      float w1 = ok1 ? spp[s1 * 2 + par] : 0.f;
      float w2 = ok2 ? spp[s2 * 2 + par] : 0.f;
      float w3 = ok3 ? spp[s3 * 2 + par] : 0.f;
      uint2 q0 = nt2[pb8 + s0 * 8 + lane8];     // 64B line / team
      uint2 q1 = nt2[pb8 + s1 * 8 + lane8];
      uint2 q2 = nt2[pb8 + s2 * 8 + lane8];
      uint2 q3 = nt2[pb8 + s3 * 8 + lane8];
      den += (w0 + w1) + (w2 + w3);
      a.x = fmaf(w0, __uint_as_float(q0.x << 16),
            fmaf(w1, __uint_as_float(q1.x << 16),
            fmaf(w2, __uint_as_float(q2.x << 16),
            fmaf(w3, __uint_as_float(q3.x << 16), a.x))));
      a.y = fmaf(w0, __uint_as_float(q0.x & 0xFFFF0000u),
            fmaf(w1, __uint_as_float(q1.x & 0xFFFF0000u),
            fmaf(w2, __uint_as_float(q2.x & 0xFFFF0000u),
            fmaf(w3, __uint_as_float(q3.x & 0xFFFF0000u), a.y))));
      a.z = fmaf(w0, __uint_as_float(q0.y << 16),
            fmaf(w1, __uint_as_float(q1.y << 16),
            fmaf(w2, __uint_as_float(q2.y << 16),
            fmaf(w3, __uint_as_float(q3.y << 16), a.z))));
      a.w = fmaf(w0, __uint_as_float(q0.y & 0xFFFF0000u),
            fmaf(w1, __uint_as_float(q1.y & 0xFFFF0000u),
            fmaf(w2, __uint_as_float(q2.y & 0xFFFF0000u),
            fmaf(w3, __uint_as_float(q3.y & 0xFFFF0000u), a.w))));
    }
    if (node < n) {
      const float inv = (deg > 0) ? 1.0f / den : 0.f;  // deg==0 -> zeros
      f32x4 o = {a.x * inv, a.y * inv, a.z * inv, a.w * inv};
      // out[node][32*hp + 4*lane8 .. +3]: 128B contiguous per team
      __builtin_nontemporal_store(
          o, (f32x4*)out + (size_t)node * 32 + (hp << 3) + lane8);
    }
  }
}

// ---------------------------------------------------------------------------
extern "C" void kernel_launch(void* const* d_in, const int* in_sizes, int n_in,
                              void* d_out, int out_size, void* d_ws, size_t ws_size,
                              hipStream_t stream) {
  const float* nodes   = (const float*)d_in[0];
  const int*   senders = (const int*)d_in[1];
  const int*   recvs   = (const int*)d_in[2];
  const float* W       = (const float*)d_in[3];
  const float* bias    = (const float*)d_in[4];
  const float* attn_w  = (const float*)d_in[5];
  // d_in[6] = attn_b: cancels in segment softmax, unused.

  const int n = in_sizes[0] / DIM;   // 100000
  const int E = in_sizes[1];         // 1600000
  const int NB = (n + BNODES - 1) >> BSHIFT;   // 1563 buckets

  char* w = (char*)d_ws;
  auto align256 = [](size_t x) { return (x + 255) & ~(size_t)255; };
  size_t off = 0;
  unsigned int* nt_hp = (unsigned int*)(w + off); off += align256((size_t)n * DIM * 2);
  float* s_exp_hp = (float*)(w + off); off += align256((size_t)n * HEADS * 4);
  unsigned int* pairs = (unsigned int*)(w + off); off += align256((size_t)NB * CAP * 4);
  int* csr_g     = (int*)(w + off);   off += align256((size_t)NB * CAP * 4);
  unsigned int* meta_g = (unsigned int*)(w + off); off += align256((size_t)NB * 64 * 4);
  int* gCursor   = (int*)(w + off);   off += align256((size_t)NB * 4);
  __bf16* Wh     = (__bf16*)(w + off); off += align256((size_t)2048 * 8 * 2);
  __bf16* Wl     = (__bf16*)(w + off); off += align256((size_t)2048 * 8 * 2);
  (void)ws_size;

  k_prepw<<<8, 256, 0, stream>>>(W, Wh, Wl, gCursor, NB);
  const int nScat = (E + 8191) / 8192;                 // 196 scatter blocks
  const int ngemm = (n + GROWS - 1) / GROWS;           // 1563 gemm blocks
  k_gemm_scatter<<<nScat + ngemm, 256, 0, stream>>>(
      nodes, Wh, Wl, bias, attn_w, nt_hp, s_exp_hp,
      senders, recvs, gCursor, pairs, E, NB, nScat, n);
  k_buildcsr<<<NB, 256, 0, stream>>>(pairs, gCursor, csr_g, meta_g);
  k_agg<<<NB * 4, 256, 0, stream>>>(csr_g, gCursor, meta_g, nt_hp, s_exp_hp,
                                    (float*)d_out, n);
}

// Round 9
// 252.089 us; speedup vs baseline: 1.2113x; 1.0391x over previous
//
#include <hip/hip_runtime.h>

#define DIM 128
#define HEADS 8
#define PHC 16

// bucket sort: 64 nodes per bucket, padded per-bucket regions
#define BSHIFT 6
#define BNODES 64
#define CAP 1408     // mean fill = E*64/n ~ 1024, sigma ~ 32; +12 sigma
#define NBMAX 1600   // >= ceil(n/64)

typedef __bf16 bf16x4 __attribute__((ext_vector_type(4)));
typedef __bf16 bf16x8 __attribute__((ext_vector_type(8)));
typedef float  f32x4  __attribute__((ext_vector_type(4)));

__device__ inline unsigned short f2bf(float x) {
  unsigned int u = __float_as_uint(x);
  unsigned int r = (u + 0x7FFF + ((u >> 16) & 1)) >> 16;  // round-to-nearest-even
  return (unsigned short)r;
}

// ---------------------------------------------------------------------------
// Kernel 0: pre-pack W into bf16 hi/lo B-fragments in MFMA fragment order,
// and zero the bucket cursors (must precede the fused gemm+scatter kernel).
// ---------------------------------------------------------------------------
__global__ __launch_bounds__(256) void k_prepw(
    const float* __restrict__ W, __bf16* __restrict__ Wh,
    __bf16* __restrict__ Wl, int* __restrict__ gCursor, int NB) {
  const int tuple = blockIdx.x * 256 + threadIdx.x;   // 0..2047
  if (tuple < NB) gCursor[tuple] = 0;
  const int ln = tuple & 15;
  const int lg = (tuple >> 4) & 3;
  const int cg = (tuple >> 6) & 7;
  const int kt = tuple >> 9;
  const int col = (cg << 4) + ln;
  bf16x8 h, l;
#pragma unroll
  for (int e = 0; e < 8; ++e) {
    int k = (kt << 5) + ((e >> 2) << 4) + (lg << 2) + (e & 3);
    float wv = W[k * DIM + col];
    __bf16 hh = (__bf16)wv;
    h[e] = hh;
    l[e] = (__bf16)(wv - (float)hh);
  }
  *(bf16x8*)(Wh + tuple * 8) = h;
  *(bf16x8*)(Wl + tuple * 8) = l;
}

// ---------------------------------------------------------------------------
// Kernel 1 (FUSED): role-split grid. Blocks [0, nScat) bucket the edge list;
// blocks [nScat, ...) run the MFMA GEMM. nt is written into 4 HEAD-PAIR
// planes nt_hp[hp][node][32ch bf16 = 64B record] plus paired exp weights
// s_exp_hp[hp][node][2 floats]. (R7-proven: absmax 0.015625. The R8
// premultiply variant FAILED accuracy — exp must stay fp32, applied at use.)
// ---------------------------------------------------------------------------
#define GROWS 64

__global__ __launch_bounds__(256, 3) void k_gemm_scatter(
    const float* __restrict__ A, const __bf16* __restrict__ Wh,
    const __bf16* __restrict__ Wl, const float* __restrict__ bias,
    const float* __restrict__ attn_w, unsigned int* __restrict__ nt_hp,
    float* __restrict__ s_exp_hp, const int* __restrict__ send,
    const int* __restrict__ recv, int* __restrict__ gCursor,
    unsigned int* __restrict__ pairs, int E, int NB, int nScat, int n) {
  __shared__ __align__(16) float smemF[GROWS * DIM];   // 32 KB, aliased

  if (blockIdx.x < nScat) {
    // ---------------- scatter role: bucket edges by recv>>6 ----------------
    int* cnt = (int*)smemF;
    int* cur = cnt + NBMAX;           // 12.8 KB of the 32 KB
    const int t = threadIdx.x;
    for (int i = t; i < NB; i += 256) cnt[i] = 0;
    __syncthreads();
    const int e0 = blockIdx.x * 8192;
    const int e1 = min(e0 + 8192, E);
    for (int i = e0 + t; i < e1; i += 256)
      atomicAdd(&cnt[recv[i] >> BSHIFT], 1);
    __syncthreads();
    for (int i = t; i < NB; i += 256) {
      int c = cnt[i];
      cur[i] = i * CAP + (c ? atomicAdd(&gCursor[i], c) : 0);
    }
    __syncthreads();
    for (int i = e0 + t; i < e1; i += 256) {
      int r = recv[i];
      int b = r >> BSHIFT;
      int p = atomicAdd(&cur[b], 1);
      if (p - b * CAP < CAP)   // overflow guard (P ~ 0 at +12 sigma)
        pairs[p] = (unsigned int)send[i] | ((unsigned int)(r & (BNODES - 1)) << 17);
    }
    return;
  }

  // ------------------------------ gemm role -------------------------------
  __bf16* Ah = (__bf16*)smemF;          // [64 rows][16 units][8] bf16 hi
  __bf16* Al = Ah + GROWS * DIM;        // same, lo
  const int t    = threadIdx.x;
  const int row0 = (blockIdx.x - nScat) * GROWS;
  const int lane = t & 63;
  const int w    = t >> 6;       // wave id: cols [32w, 32w+32)
  const int lg   = lane >> 4;    // k-group
  const int ln   = lane & 15;    // fragment row (A) / col (B,D)

  // ---- A-tile global loads
  float4 av[8];
  {
    const float4* A4 = (const float4*)(A + (size_t)row0 * DIM);
    const int lim = min(GROWS, n - row0) * (DIM / 4);
#pragma unroll
    for (int j = 0; j < 8; ++j) {
      int i = t + j * 256;
      av[j] = (i < lim) ? A4[i] : make_float4(0.f, 0.f, 0.f, 0.f);
    }
  }

  // ---- convert to bf16 hi/lo, store fragment-ordered + swizzled.
#pragma unroll
  for (int j = 0; j < 8; ++j) {
    int i = t + j * 256;
    int r = i >> 5, c4 = i & 31;
    int ktc = c4 >> 3, lgc = c4 & 3, ehi = (c4 >> 2) & 1;
    int unit = (r << 4) + (((ktc << 2) + lgc) ^ (r & 15));
    int ei = (unit << 3) + (ehi << 2);
    float x0 = av[j].x, x1 = av[j].y, x2 = av[j].z, x3 = av[j].w;
    __bf16 h0 = (__bf16)x0, h1 = (__bf16)x1, h2 = (__bf16)x2, h3 = (__bf16)x3;
    bf16x4 hv = {h0, h1, h2, h3};
    bf16x4 lv = {(__bf16)(x0 - (float)h0), (__bf16)(x1 - (float)h1),
                 (__bf16)(x2 - (float)h2), (__bf16)(x3 - (float)h3)};
    *(bf16x4*)(Ah + ei) = hv;
    *(bf16x4*)(Al + ei) = lv;
  }

  f32x4 acc[4][2];
  {
    const float b0 = bias[(w << 5) + ln];
    const float b1 = bias[(w << 5) + 16 + ln];
#pragma unroll
    for (int rt = 0; rt < 4; ++rt) {
      acc[rt][0] = (f32x4){b0, b0, b0, b0};
      acc[rt][1] = (f32x4){b1, b1, b1, b1};
    }
  }
  __syncthreads();

  // ---- main loop: 4 k-steps x {4 W vec-loads, 8 ds_read_b128, 24 MFMA}
  const int cg0 = w << 1;
#pragma unroll
  for (int kt = 0; kt < 4; ++kt) {
    bf16x8 Bh0, Bl0, Bh1, Bl1;
    {
      int i0 = ((((kt << 3) + cg0) << 2) + lg) * 16 + ln;      // ct = 0
      int i1 = ((((kt << 3) + cg0 + 1) << 2) + lg) * 16 + ln;  // ct = 1
      Bh0 = *(const bf16x8*)(Wh + (i0 << 3));
      Bl0 = *(const bf16x8*)(Wl + (i0 << 3));
      Bh1 = *(const bf16x8*)(Wh + (i1 << 3));
      Bl1 = *(const bf16x8*)(Wl + (i1 << 3));
    }
    bf16x8 ah[4], al[4];
#pragma unroll
    for (int rt = 0; rt < 4; ++rt) {
      int m = (rt << 4) + ln;
      int u = (m << 4) + (((kt << 2) + lg) ^ (m & 15));
      ah[rt] = *(const bf16x8*)(Ah + (u << 3));
      al[rt] = *(const bf16x8*)(Al + (u << 3));
    }
#pragma unroll
    for (int rt = 0; rt < 4; ++rt) {
      acc[rt][0] = __builtin_amdgcn_mfma_f32_16x16x32_bf16(ah[rt], Bh0, acc[rt][0], 0, 0, 0);
      acc[rt][0] = __builtin_amdgcn_mfma_f32_16x16x32_bf16(ah[rt], Bl0, acc[rt][0], 0, 0, 0);
      acc[rt][0] = __builtin_amdgcn_mfma_f32_16x16x32_bf16(al[rt], Bh0, acc[rt][0], 0, 0, 0);
      acc[rt][1] = __builtin_amdgcn_mfma_f32_16x16x32_bf16(ah[rt], Bh1, acc[rt][1], 0, 0, 0);
      acc[rt][1] = __builtin_amdgcn_mfma_f32_16x16x32_bf16(ah[rt], Bl1, acc[rt][1], 0, 0, 0);
      acc[rt][1] = __builtin_amdgcn_mfma_f32_16x16x32_bf16(al[rt], Bh1, acc[rt][1], 0, 0, 0);
    }
  }

  __syncthreads();   // all waves done with Ah/Al -> reuse LDS as f32 scratch

  // ---- scatter D-fragments to LDS f32 [64][128] (col bit4 ^= row bit2)
#pragma unroll
  for (int rt = 0; rt < 4; ++rt)
#pragma unroll
    for (int ct = 0; ct < 2; ++ct) {
      int colx = ((w << 5) + (ct << 4) + ln) ^ ((lg & 1) << 4);
#pragma unroll
      for (int r = 0; r < 4; ++r) {
        int rowl = (rt << 4) + (lg << 2) + r;
        smemF[(rowl << 7) + colx] = acc[rt][ct][r];
      }
    }

  // ---- sender scores from register fragments -> paired exp planes.
  //      receiver part + attn_b cancel in the segment softmax; |score|<=~6.
  {
    const float aw = attn_w[ln];
#pragma unroll
    for (int rt = 0; rt < 4; ++rt)
#pragma unroll
      for (int ct = 0; ct < 2; ++ct) {
        // head = 2w + ct -> head-pair hp = w, parity = ct
#pragma unroll
        for (int r = 0; r < 4; ++r) {
          float v = acc[rt][ct][r];
          float p = (v > 0.f ? v : 0.2f * v) * aw;
          p += __shfl_xor(p, 1);
          p += __shfl_xor(p, 2);
          p += __shfl_xor(p, 4);
          p += __shfl_xor(p, 8);
          if (ln == 0) {
            int row = row0 + (rt << 4) + (lg << 2) + r;
            if (row < n) s_exp_hp[((size_t)w * n + row) * 2 + ct] = __expf(p);
          }
        }
      }
  }
  __syncthreads();

  // ---- pack to bf16 from LDS into head-pair planes:
  //      nt_hp[hp][node][32ch] (64B record). Same f2bf rounding -> absmax
  //      unchanged. Each j writes one head's 16ch slice of its pair plane.
  {
    const int nrow = min(GROWS, n - row0);
    const int r = t >> 2;           // 0..63 row in tile
    const int q = t & 3;            // 4-ch group within the head slice
    if (r < nrow) {
#pragma unroll
      for (int j = 0; j < 8; ++j) { // j = head
        int c4 = (j << 2) + q;
        int c4s = c4 ^ (((r >> 2) & 1) << 2);   // undo col-bit4 swizzle
        f32x4 v = *(const f32x4*)(smemF + (r << 7) + (c4s << 2));
        unsigned int lo = (unsigned int)f2bf(v[0]) | ((unsigned int)f2bf(v[1]) << 16);
        unsigned int hi = (unsigned int)f2bf(v[2]) | ((unsigned int)f2bf(v[3]) << 16);
        ((uint2*)nt_hp)[((size_t)(j >> 1) * n + row0 + r) * 8 + (j & 1) * 4 + q] =
            make_uint2(lo, hi);
      }
    }
  }
}

// ---------------------------------------------------------------------------
// Kernel 2: FUSED build + aggregate. Grid NB*4, block = (bucket, head-pair);
// hp = blockIdx & 3 -> XCDs {x, x+4} own plane hp (R5/R7-verified L2 story).
// Build (hist + scan + rank-sort + CSR scatter) runs once per block (4x per
// bucket) — R6 proved the build hides under gather memory time, while its
// separate dispatch cost ~15-25 us. Aggregate: 8-lane team per degree-sorted
// slot, one 64B u-record line + one 8B exp request per edge-hp, unroll x8.
// ---------------------------------------------------------------------------
__global__ __launch_bounds__(256) void k_aggbuild(
    const unsigned int* __restrict__ pairs, const int* __restrict__ gCursor,
    const unsigned int* __restrict__ nt_hp, const float* __restrict__ s_exp_hp,
    float* __restrict__ out, int n) {
  __shared__ unsigned int buf[CAP];
  __shared__ int csr_l[CAP];
  __shared__ int hist[BNODES], curl[BNODES];
  __shared__ unsigned int slotmeta[BNODES];
  const int b  = blockIdx.x >> 2;
  const int hp = blockIdx.x & 3;    // head pair; blockIdx%8 ~ XCD round-robin
  const int t = threadIdx.x;
  const int base = b * CAP;
  const int bsize = min(gCursor[b], CAP);

  // ---- build phase (free under the gather's memory time, per R6)
  for (int i = t; i < bsize; i += 256)
    buf[i] = __builtin_nontemporal_load(&pairs[base + i]);
  if (t < BNODES) hist[t] = 0;
  __syncthreads();
  for (int i = t; i < bsize; i += 256)
    atomicAdd(&hist[(buf[i] >> 17) & (BNODES - 1)], 1);
  __syncthreads();
  if (t < 64) {   // wave 0: scan for offsets + counting-rank degree sort
    int v = hist[t];
    int x = v;
#pragma unroll
    for (int off = 1; off < 64; off <<= 1) {
      int y = __shfl_up(x, off);
      if (t >= off) x += y;
    }
    int e = x - v;          // exclusive offset
    curl[t] = e;
    int rank = 0;
    for (int j = 0; j < 64; ++j) {
      int dj = hist[j];
      rank += (dj > v) || (dj == v && j < t);
    }
    slotmeta[rank] = ((unsigned int)e << 17) | ((unsigned int)v << 6) |
                     (unsigned int)t;
  }
  __syncthreads();
  for (int i = t; i < bsize; i += 256) {
    unsigned int v = buf[i];
    int p = atomicAdd(&curl[(v >> 17) & (BNODES - 1)], 1);
    csr_l[p] = (int)(v & 0x1FFFF);
  }
  __syncthreads();

  // ---- aggregate phase: 8-lane team per degree-sorted slot
  const int lane8 = t & 7;        // owns channels 4*lane8 .. +3 of the 32
  const int par   = lane8 >> 2;   // head parity within the pair
  const uint2* nt2 = (const uint2*)nt_hp;
  const size_t pb8 = (size_t)hp * n * 8;        // plane base, uint2 units
  const float* spp = s_exp_hp + (size_t)hp * n * 2;

#pragma unroll 1
  for (int pi = 0; pi < 2; ++pi) {
    const int nl = (t >> 3) + (pi << 5);        // degree-sorted slot
    const unsigned int m = slotmeta[nl];
    const int node = (b << BSHIFT) + (int)(m & 63);
    const int deg  = (int)((m >> 6) & 0x7FF);
    const int eoff = (int)(m >> 17);
    f32x4 a = {0.f, 0.f, 0.f, 0.f};
    float den = 0.f;
    for (int j = 0; j < deg; j += 8) {
      int   ss[8];
      float ww[8];
      uint2 qq[8];
#pragma unroll
      for (int u = 0; u < 8; ++u) {
        bool ok = (j + u) < deg;
        ss[u] = csr_l[ok ? (eoff + j + u) : eoff];
        ww[u] = ok ? spp[ss[u] * 2 + par] : 0.f;  // 8B line / team
        qq[u] = nt2[pb8 + ss[u] * 8 + lane8];     // 64B line / team
      }
#pragma unroll
      for (int u = 0; u < 8; ++u) {
        den += ww[u];
        a.x = fmaf(ww[u], __uint_as_float(qq[u].x << 16), a.x);
        a.y = fmaf(ww[u], __uint_as_float(qq[u].x & 0xFFFF0000u), a.y);
        a.z = fmaf(ww[u], __uint_as_float(qq[u].y << 16), a.z);
        a.w = fmaf(ww[u], __uint_as_float(qq[u].y & 0xFFFF0000u), a.w);
      }
    }
    if (node < n) {
      const float inv = (deg > 0) ? 1.0f / den : 0.f;  // deg==0 -> zeros
      f32x4 o = {a.x * inv, a.y * inv, a.z * inv, a.w * inv};
      // out[node][32*hp + 4*lane8 .. +3]: 128B contiguous per team
      __builtin_nontemporal_store(
          o, (f32x4*)out + (size_t)node * 32 + (hp << 3) + lane8);
    }
  }
}

// ---------------------------------------------------------------------------
extern "C" void kernel_launch(void* const* d_in, const int* in_sizes, int n_in,
                              void* d_out, int out_size, void* d_ws, size_t ws_size,
                              hipStream_t stream) {
  const float* nodes   = (const float*)d_in[0];
  const int*   senders = (const int*)d_in[1];
  const int*   recvs   = (const int*)d_in[2];
  const float* W       = (const float*)d_in[3];
  const float* bias    = (const float*)d_in[4];
  const float* attn_w  = (const float*)d_in[5];
  // d_in[6] = attn_b: cancels in segment softmax, unused.

  const int n = in_sizes[0] / DIM;   // 100000
  const int E = in_sizes[1];         // 1600000
  const int NB = (n + BNODES - 1) >> BSHIFT;   // 1563 buckets

  char* w = (char*)d_ws;
  auto align256 = [](size_t x) { return (x + 255) & ~(size_t)255; };
  size_t off = 0;
  unsigned int* nt_hp = (unsigned int*)(w + off); off += align256((size_t)n * DIM * 2);
  float* s_exp_hp = (float*)(w + off); off += align256((size_t)n * HEADS * 4);
  unsigned int* pairs = (unsigned int*)(w + off); off += align256((size_t)NB * CAP * 4);
  int* gCursor   = (int*)(w + off);   off += align256((size_t)NB * 4);
  __bf16* Wh     = (__bf16*)(w + off); off += align256((size_t)2048 * 8 * 2);
  __bf16* Wl     = (__bf16*)(w + off); off += align256((size_t)2048 * 8 * 2);
  (void)ws_size;

  k_prepw<<<8, 256, 0, stream>>>(W, Wh, Wl, gCursor, NB);
  const int nScat = (E + 8191) / 8192;                 // 196 scatter blocks
  const int ngemm = (n + GROWS - 1) / GROWS;           // 1563 gemm blocks
  k_gemm_scatter<<<nScat + ngemm, 256, 0, stream>>>(
      nodes, Wh, Wl, bias, attn_w, nt_hp, s_exp_hp,
      senders, recvs, gCursor, pairs, E, NB, nScat, n);
  k_aggbuild<<<NB * 4, 256, 0, stream>>>(pairs, gCursor, nt_hp, s_exp_hp,
                                         (float*)d_out, n);
}